// Round 1
// baseline (304.442 us; speedup 1.0000x reference)
//
#include <hip/hip_runtime.h>
#include <hip/hip_bf16.h>
#include <math.h>

typedef __attribute__((ext_vector_type(4))) float f32x4;
typedef __attribute__((ext_vector_type(8))) short s16x8;

#define LDSP(p) ((__attribute__((address_space(3))) void*)(p))
#define GLBP(p) ((const __attribute__((address_space(1))) void*)(p))

__device__ __forceinline__ unsigned short f2b(float f) {
  unsigned u = __builtin_bit_cast(unsigned, f);
  u += 0x7FFFu + ((u >> 16) & 1u);
  return (unsigned short)(u >> 16);
}
__device__ __forceinline__ float b2f(unsigned short h) {
  unsigned u = ((unsigned)h) << 16;
  return __builtin_bit_cast(float, u);
}

// ---------------- fp32 -> bf16 convert (vectorized, 8 elems/thread) ----------------
__global__ void cvt_f2b_kernel(const float* __restrict__ src, unsigned short* __restrict__ dst, int n8) {
  int i = blockIdx.x * blockDim.x + threadIdx.x;
  if (i >= n8) return;
  const float4* s = (const float4*)src;
  float4 a = s[2 * i], b = s[2 * i + 1];
  s16x8 o;
  o[0] = (short)f2b(a.x); o[1] = (short)f2b(a.y); o[2] = (short)f2b(a.z); o[3] = (short)f2b(a.w);
  o[4] = (short)f2b(b.x); o[5] = (short)f2b(b.y); o[6] = (short)f2b(b.z); o[7] = (short)f2b(b.w);
  ((s16x8*)dst)[i] = o;
}

// ---------------- RoPE cos/sin table: [2048][32] ----------------
__global__ void rope_table_kernel(float* __restrict__ cosT, float* __restrict__ sinT) {
  int idx = blockIdx.x * 256 + threadIdx.x;  // 65536
  int s = idx >> 5, j = idx & 31;
  float freq = (float)(1.0 / pow(10000.0, (double)(2 * j) / 64.0));
  float fm = (float)s * freq;
  cosT[idx] = cosf(fm);
  sinT[idx] = sinf(fm);
}

// ---------------- RoPE in-place on [b*h][s][64] bf16, fused scale ----------------
__global__ void rope_apply_kernel(unsigned short* __restrict__ qk, const float* __restrict__ cosT,
                                  const float* __restrict__ sinT, float scale) {
  int i = blockIdx.x * 256 + threadIdx.x;  // 1048576 groups of 8 elems
  int e = i * 8;
  int s = (e >> 6) & 2047;
  int jb = (e & 63) >> 1;   // pair index base (0,4,...,28)
  s16x8 v = ((const s16x8*)qk)[i];
  float4 c = *(const float4*)(cosT + s * 32 + jb);
  float4 sn = *(const float4*)(sinT + s * 32 + jb);
  float cc[4] = {c.x, c.y, c.z, c.w}, ss[4] = {sn.x, sn.y, sn.z, sn.w};
  s16x8 o;
#pragma unroll
  for (int p = 0; p < 4; ++p) {
    float e_ = b2f((unsigned short)v[2 * p]);
    float o_ = b2f((unsigned short)v[2 * p + 1]);
    o[2 * p]     = (short)f2b((e_ * cc[p] - o_ * ss[p]) * scale);
    o[2 * p + 1] = (short)f2b((e_ * ss[p] + o_ * cc[p]) * scale);
  }
  ((s16x8*)qk)[i] = o;
}

// ---------------- GEMM: C[m][n] = sum_k A[m][k] * B[n][k]  (B^T layout) ----------------
// 128x128 tile, BK=64, 4 waves (2x2), 16x16x32 bf16 MFMA, global_load_lds w=16,
// XOR-swizzled LDS (pre-swizzled global source; linear LDS dest).
// EPI=0: write fp32 C row-major [M][N].  EPI=1: QKV split + permute to [b,h,s,dk] bf16.
template <int EPI>
__global__ void gemm_bt_kernel(const unsigned short* __restrict__ A, const unsigned short* __restrict__ B,
                               float* __restrict__ Cf, unsigned short* __restrict__ Cq,
                               unsigned short* __restrict__ Ck, unsigned short* __restrict__ Cv,
                               int M, int N, int K) {
  __shared__ __align__(16) unsigned short As[128 * 64];
  __shared__ __align__(16) unsigned short Bs[128 * 64];
  const int t = threadIdx.x;
  const int lane = t & 63, wave = t >> 6;
  const int wm = wave >> 1, wn = wave & 1;
  const int g = lane >> 4, q = lane & 15;
  const int m0 = blockIdx.x * 128, n0 = blockIdx.y * 128;
  const int srow = t >> 3;            // 0..31
  const int scol = (t & 7) << 4;      // byte col 0..112
  f32x4 acc[4][4] = {};
  const int nkt = K >> 6;
  for (int kt = 0; kt < nkt; ++kt) {
    __syncthreads();
#pragma unroll
    for (int it = 0; it < 4; ++it) {
      int row = it * 32 + srow;
      int cg = scol ^ ((row & 7) << 4);   // inverse-swizzle the SOURCE, LDS dest linear
      const char* ga = (const char*)A + ((size_t)(m0 + row) * K + (kt << 6)) * 2 + cg;
      __builtin_amdgcn_global_load_lds(GLBP(ga), LDSP((char*)As + it * 4096 + wave * 1024), 16, 0, 0);
      const char* gb = (const char*)B + ((size_t)(n0 + row) * K + (kt << 6)) * 2 + cg;
      __builtin_amdgcn_global_load_lds(GLBP(gb), LDSP((char*)Bs + it * 4096 + wave * 1024), 16, 0, 0);
    }
    asm volatile("s_waitcnt vmcnt(0)" ::: "memory");
    __syncthreads();
#pragma unroll
    for (int kk = 0; kk < 2; ++kk) {
      const int colB = ((kk << 6) + (g << 4)) ^ ((q & 7) << 4);  // swizzled read col (bytes)
      s16x8 af[4], bf[4];
#pragma unroll
      for (int x = 0; x < 4; ++x) {
        af[x] = *(const s16x8*)(As + (wm * 64 + x * 16 + q) * 64 + (colB >> 1));
        bf[x] = *(const s16x8*)(Bs + (wn * 64 + x * 16 + q) * 64 + (colB >> 1));
      }
#pragma unroll
      for (int mi = 0; mi < 4; ++mi)
#pragma unroll
        for (int ni = 0; ni < 4; ++ni)
          acc[mi][ni] = __builtin_amdgcn_mfma_f32_16x16x32_bf16(af[mi], bf[ni], acc[mi][ni], 0, 0, 0);
    }
  }
  if (EPI == 0) {
#pragma unroll
    for (int mi = 0; mi < 4; ++mi)
#pragma unroll
      for (int r = 0; r < 4; ++r) {
        int m = m0 + wm * 64 + mi * 16 + g * 4 + r;
#pragma unroll
        for (int ni = 0; ni < 4; ++ni) {
          int n = n0 + wn * 64 + ni * 16 + q;
          Cf[(size_t)m * N + n] = acc[mi][ni][r];
        }
      }
  } else {
    unsigned short* dst = (n0 < 1024) ? Cq : (n0 < 2048 ? Ck : Cv);
    const int obase = n0 & 1023;
#pragma unroll
    for (int mi = 0; mi < 4; ++mi)
#pragma unroll
      for (int r = 0; r < 4; ++r) {
        int m = m0 + wm * 64 + mi * 16 + g * 4 + r;
        int bb = m >> 11, s = m & 2047;
#pragma unroll
        for (int ni = 0; ni < 4; ++ni) {
          int o = obase + wn * 64 + ni * 16 + q;
          int hh = o >> 6, d = o & 63;
          dst[(((size_t)bb * 16 + hh) * 2048 + s) * 64 + d] = f2b(acc[mi][ni][r]);
        }
      }
  }
}

// ---------------- Flash attention: grid (64 heads, 32 q-tiles), 4 waves/block ----------------
// Each wave owns 16 q-rows. KVBLK=64. K via swizzled global_load_lds; V transposed into
// padded LDS (stride 72); P through per-wave padded LDS.
__global__ void attn_kernel(const unsigned short* __restrict__ Q, const unsigned short* __restrict__ K,
                            const unsigned short* __restrict__ V, unsigned short* __restrict__ O) {
  __shared__ __align__(16) unsigned short Ks[64 * 64];
  __shared__ __align__(16) unsigned short Vt[64 * 72];
  __shared__ __align__(16) unsigned short Ps[4 * 16 * 72];
  const int t = threadIdx.x;
  const int lane = t & 63, w = t >> 6;
  const int g = lane >> 4, q = lane & 15;
  const int bh = blockIdx.x;
  const int qt = 31 - (int)blockIdx.y;   // big q-tiles (most work) first
  const size_t hoff = (size_t)bh * 2048 * 64;
  s16x8 qa[2];
  {
    const unsigned short* qp = Q + hoff + (size_t)(qt * 64 + w * 16 + q) * 64 + g * 8;
    qa[0] = *(const s16x8*)qp;
    qa[1] = *(const s16x8*)(qp + 32);
  }
  f32x4 accO[4] = {};
  float mrun[4] = {-3e38f, -3e38f, -3e38f, -3e38f};
  float lrun[4] = {0.f, 0.f, 0.f, 0.f};
  const int srow = t >> 3;
  const int scol = (t & 7) << 4;
  unsigned short* pw = Ps + w * (16 * 72);
  for (int tk = 0; tk <= qt; ++tk) {
    __syncthreads();
    // ---- stage K tile (swizzled source -> linear LDS) ----
    const char* kb = (const char*)(K + hoff + (size_t)tk * 4096);
#pragma unroll
    for (int it = 0; it < 2; ++it) {
      int row = it * 32 + srow;
      int cg = scol ^ ((row & 7) << 4);
      __builtin_amdgcn_global_load_lds(GLBP(kb + row * 128 + cg), LDSP((char*)Ks + it * 4096 + w * 1024), 16, 0, 0);
    }
    // ---- stage V transposed: Vt[d][kv], stride 72 (pad kills bank conflicts) ----
    {
      const unsigned short* vb = V + hoff + (size_t)tk * 4096;
#pragma unroll
      for (int p = 0; p < 2; ++p) {
        int d0 = w * 8 + p * 32;
        s16x8 vv = *(const s16x8*)(vb + lane * 64 + d0);
#pragma unroll
        for (int j = 0; j < 8; ++j) Vt[(d0 + j) * 72 + lane] = (unsigned short)vv[j];
      }
    }
    asm volatile("s_waitcnt vmcnt(0)" ::: "memory");
    __syncthreads();
    // ---- S = Q*K^T (16x64 per wave) ----
    f32x4 accS[4] = {};
#pragma unroll
    for (int kk = 0; kk < 2; ++kk) {
      const int colB = ((kk << 6) + (g << 4)) ^ ((q & 7) << 4);
      s16x8 kf[4];
#pragma unroll
      for (int ni = 0; ni < 4; ++ni)
        kf[ni] = *(const s16x8*)(Ks + (ni * 16 + q) * 64 + (colB >> 1));
#pragma unroll
      for (int ni = 0; ni < 4; ++ni)
        accS[ni] = __builtin_amdgcn_mfma_f32_16x16x32_bf16(qa[kk], kf[ni], accS[ni], 0, 0, 0);
    }
    // ---- causal mask (diagonal tile only) ----
    if (tk == qt) {
#pragma unroll
      for (int ni = 0; ni < 4; ++ni)
#pragma unroll
        for (int r = 0; r < 4; ++r) {
          int qrow = w * 16 + g * 4 + r;
          int kvc = ni * 16 + q;
          if (kvc > qrow) accS[ni][r] = -3e38f;
        }
    }
    // ---- online softmax (row-reduce across 16 lanes sharing a row) ----
    float alph[4];
#pragma unroll
    for (int r = 0; r < 4; ++r) {
      float mx = fmaxf(fmaxf(accS[0][r], accS[1][r]), fmaxf(accS[2][r], accS[3][r]));
      mx = fmaxf(mx, __shfl_xor(mx, 1));
      mx = fmaxf(mx, __shfl_xor(mx, 2));
      mx = fmaxf(mx, __shfl_xor(mx, 4));
      mx = fmaxf(mx, __shfl_xor(mx, 8));
      float mnew = fmaxf(mrun[r], mx);
      float sum = 0.f;
#pragma unroll
      for (int ni = 0; ni < 4; ++ni) {
        float p = __expf(accS[ni][r] - mnew);
        accS[ni][r] = p;
        sum += p;
      }
      sum += __shfl_xor(sum, 1);
      sum += __shfl_xor(sum, 2);
      sum += __shfl_xor(sum, 4);
      sum += __shfl_xor(sum, 8);
      float alpha = __expf(mrun[r] - mnew);
      lrun[r] = lrun[r] * alpha + sum;
      mrun[r] = mnew;
      alph[r] = alpha;
    }
#pragma unroll
    for (int ni = 0; ni < 4; ++ni)
#pragma unroll
      for (int r = 0; r < 4; ++r) accO[ni][r] *= alph[r];
    // ---- P (C-layout) -> per-wave LDS -> A-fragment layout ----
#pragma unroll
    for (int ni = 0; ni < 4; ++ni)
#pragma unroll
      for (int r = 0; r < 4; ++r)
        pw[(g * 4 + r) * 72 + ni * 16 + q] = f2b(accS[ni][r]);
    // (same-wave DS ordering is in-order; wave-private buffer, no barrier needed)
#pragma unroll
    for (int kk = 0; kk < 2; ++kk) {
      s16x8 pa = *(const s16x8*)(pw + q * 72 + kk * 32 + g * 8);
#pragma unroll
      for (int ni = 0; ni < 4; ++ni) {
        s16x8 vf = *(const s16x8*)(Vt + (ni * 16 + q) * 72 + kk * 32 + g * 8);
        accO[ni] = __builtin_amdgcn_mfma_f32_16x16x32_bf16(pa, vf, accO[ni], 0, 0, 0);
      }
    }
  }
  // ---- epilogue: O /= l, write [b][s][h*64+d] bf16 ----
  const int bb = bh >> 4, hh = bh & 15;
#pragma unroll
  for (int ni = 0; ni < 4; ++ni)
#pragma unroll
    for (int r = 0; r < 4; ++r) {
      int s = qt * 64 + w * 16 + g * 4 + r;
      O[((size_t)(bb * 2048 + s)) * 1024 + hh * 64 + ni * 16 + q] = f2b(accO[ni][r] / lrun[r]);
    }
}

// ---------------- launch ----------------
extern "C" void kernel_launch(void* const* d_in, const int* in_sizes, int n_in,
                              void* d_out, int out_size, void* d_ws, size_t ws_size,
                              hipStream_t stream) {
  const float* x  = (const float*)d_in[0];
  const float* Wq = (const float*)d_in[1];
  const float* Wk = (const float*)d_in[2];
  const float* Wv = (const float*)d_in[3];
  const float* Wo = (const float*)d_in[4];
  char* ws = (char*)d_ws;
  unsigned short* xb   = (unsigned short*)(ws);               // 16 MB  [8192][1024]
  unsigned short* wqkv = (unsigned short*)(ws + 16777216);    // 6 MB   [3072][1024]
  unsigned short* wo   = (unsigned short*)(ws + 23068672);    // 2 MB   [1024][1024]
  unsigned short* qb   = (unsigned short*)(ws + 25165824);    // 16 MB  [64][2048][64]
  unsigned short* kb   = (unsigned short*)(ws + 41943040);    // 16 MB
  unsigned short* vb   = (unsigned short*)(ws + 58720256);    // 16 MB
  unsigned short* ab   = (unsigned short*)(ws + 75497472);    // 16 MB  [8192][1024]
  float* cosT = (float*)(ws + 92274688);                      // 256 KB
  float* sinT = (float*)(ws + 92536832);                      // 256 KB

  cvt_f2b_kernel<<<4096, 256, 0, stream>>>(x, xb, 1048576);
  cvt_f2b_kernel<<<512, 256, 0, stream>>>(Wq, wqkv, 131072);
  cvt_f2b_kernel<<<512, 256, 0, stream>>>(Wk, wqkv + 1048576, 131072);
  cvt_f2b_kernel<<<512, 256, 0, stream>>>(Wv, wqkv + 2097152, 131072);
  cvt_f2b_kernel<<<512, 256, 0, stream>>>(Wo, wo, 131072);
  rope_table_kernel<<<256, 256, 0, stream>>>(cosT, sinT);
  gemm_bt_kernel<1><<<dim3(64, 24), 256, 0, stream>>>(xb, wqkv, nullptr, qb, kb, vb, 8192, 3072, 1024);
  rope_apply_kernel<<<4096, 256, 0, stream>>>(qb, cosT, sinT, 0.125f);  // fold 1/sqrt(dk) into Q
  rope_apply_kernel<<<4096, 256, 0, stream>>>(kb, cosT, sinT, 1.0f);
  attn_kernel<<<dim3(64, 32), 256, 0, stream>>>(qb, kb, vb, ab);
  gemm_bt_kernel<0><<<dim3(64, 8), 256, 0, stream>>>(ab, wo, (float*)d_out, nullptr, nullptr, nullptr, 8192, 1024, 1024);
}

// Round 2
// 277.944 us; speedup vs baseline: 1.0953x; 1.0953x over previous
//
#include <hip/hip_runtime.h>
#include <hip/hip_bf16.h>
#include <math.h>

typedef __attribute__((ext_vector_type(4))) float f32x4;
typedef __attribute__((ext_vector_type(16))) float f32x16;
typedef __attribute__((ext_vector_type(8))) short s16x8;
typedef __attribute__((ext_vector_type(4))) unsigned u32x4;

#define LDSP(p) ((__attribute__((address_space(3))) void*)(p))
#define GLBP(p) ((const __attribute__((address_space(1))) void*)(p))

__device__ __forceinline__ unsigned short f2b(float f) {
  unsigned u = __builtin_bit_cast(unsigned, f);
  u += 0x7FFFu + ((u >> 16) & 1u);
  return (unsigned short)(u >> 16);
}
__device__ __forceinline__ float b2f(unsigned short h) {
  unsigned u = ((unsigned)h) << 16;
  return __builtin_bit_cast(float, u);
}
__device__ __forceinline__ unsigned cvtpk_bf16(float lo, float hi) {
  unsigned r;
  asm("v_cvt_pk_bf16_f32 %0, %1, %2" : "=v"(r) : "v"(lo), "v"(hi));
  return r;
}

// ---------------- fp32 -> bf16 convert (vectorized, 8 elems/thread) ----------------
__global__ void cvt_f2b_kernel(const float* __restrict__ src, unsigned short* __restrict__ dst, int n8) {
  int i = blockIdx.x * blockDim.x + threadIdx.x;
  if (i >= n8) return;
  const float4* s = (const float4*)src;
  float4 a = s[2 * i], b = s[2 * i + 1];
  s16x8 o;
  o[0] = (short)f2b(a.x); o[1] = (short)f2b(a.y); o[2] = (short)f2b(a.z); o[3] = (short)f2b(a.w);
  o[4] = (short)f2b(b.x); o[5] = (short)f2b(b.y); o[6] = (short)f2b(b.z); o[7] = (short)f2b(b.w);
  ((s16x8*)dst)[i] = o;
}

// ---------------- RoPE cos/sin table: [2048][32] ----------------
__global__ void rope_table_kernel(float* __restrict__ cosT, float* __restrict__ sinT) {
  int idx = blockIdx.x * 256 + threadIdx.x;  // 65536
  int s = idx >> 5, j = idx & 31;
  float freq = (float)(1.0 / pow(10000.0, (double)(2 * j) / 64.0));
  float fm = (float)s * freq;
  cosT[idx] = cosf(fm);
  sinT[idx] = sinf(fm);
}

// ---------------- RoPE in-place on [b*h][s][64] bf16, fused scale ----------------
__global__ void rope_apply_kernel(unsigned short* __restrict__ qk, const float* __restrict__ cosT,
                                  const float* __restrict__ sinT, float scale) {
  int i = blockIdx.x * 256 + threadIdx.x;  // 1048576 groups of 8 elems
  int e = i * 8;
  int s = (e >> 6) & 2047;
  int jb = (e & 63) >> 1;
  s16x8 v = ((const s16x8*)qk)[i];
  float4 c = *(const float4*)(cosT + s * 32 + jb);
  float4 sn = *(const float4*)(sinT + s * 32 + jb);
  float cc[4] = {c.x, c.y, c.z, c.w}, ss[4] = {sn.x, sn.y, sn.z, sn.w};
  s16x8 o;
#pragma unroll
  for (int p = 0; p < 4; ++p) {
    float e_ = b2f((unsigned short)v[2 * p]);
    float o_ = b2f((unsigned short)v[2 * p + 1]);
    o[2 * p]     = (short)f2b((e_ * cc[p] - o_ * ss[p]) * scale);
    o[2 * p + 1] = (short)f2b((e_ * ss[p] + o_ * cc[p]) * scale);
  }
  ((s16x8*)qk)[i] = o;
}

// ---------------- GEMM: C[m][n] = sum_k A[m][k] * B[n][k]  (B^T layout) ----------------
template <int EPI>
__global__ void gemm_bt_kernel(const unsigned short* __restrict__ A, const unsigned short* __restrict__ B,
                               float* __restrict__ Cf, unsigned short* __restrict__ Cq,
                               unsigned short* __restrict__ Ck, unsigned short* __restrict__ Cv,
                               int M, int N, int K) {
  __shared__ __align__(16) unsigned short As[128 * 64];
  __shared__ __align__(16) unsigned short Bs[128 * 64];
  const int t = threadIdx.x;
  const int lane = t & 63, wave = t >> 6;
  const int wm = wave >> 1, wn = wave & 1;
  const int g = lane >> 4, q = lane & 15;
  const int m0 = blockIdx.x * 128, n0 = blockIdx.y * 128;
  const int srow = t >> 3;
  const int scol = (t & 7) << 4;
  f32x4 acc[4][4] = {};
  const int nkt = K >> 6;
  for (int kt = 0; kt < nkt; ++kt) {
    __syncthreads();
#pragma unroll
    for (int it = 0; it < 4; ++it) {
      int row = it * 32 + srow;
      int cg = scol ^ ((row & 7) << 4);
      const char* ga = (const char*)A + ((size_t)(m0 + row) * K + (kt << 6)) * 2 + cg;
      __builtin_amdgcn_global_load_lds(GLBP(ga), LDSP((char*)As + it * 4096 + wave * 1024), 16, 0, 0);
      const char* gb = (const char*)B + ((size_t)(n0 + row) * K + (kt << 6)) * 2 + cg;
      __builtin_amdgcn_global_load_lds(GLBP(gb), LDSP((char*)Bs + it * 4096 + wave * 1024), 16, 0, 0);
    }
    asm volatile("s_waitcnt vmcnt(0)" ::: "memory");
    __syncthreads();
#pragma unroll
    for (int kk = 0; kk < 2; ++kk) {
      const int colB = ((kk << 6) + (g << 4)) ^ ((q & 7) << 4);
      s16x8 af[4], bf[4];
#pragma unroll
      for (int x = 0; x < 4; ++x) {
        af[x] = *(const s16x8*)(As + (wm * 64 + x * 16 + q) * 64 + (colB >> 1));
        bf[x] = *(const s16x8*)(Bs + (wn * 64 + x * 16 + q) * 64 + (colB >> 1));
      }
#pragma unroll
      for (int mi = 0; mi < 4; ++mi)
#pragma unroll
        for (int ni = 0; ni < 4; ++ni)
          acc[mi][ni] = __builtin_amdgcn_mfma_f32_16x16x32_bf16(af[mi], bf[ni], acc[mi][ni], 0, 0, 0);
    }
  }
  if (EPI == 0) {
#pragma unroll
    for (int mi = 0; mi < 4; ++mi)
#pragma unroll
      for (int r = 0; r < 4; ++r) {
        int m = m0 + wm * 64 + mi * 16 + g * 4 + r;
#pragma unroll
        for (int ni = 0; ni < 4; ++ni) {
          int n = n0 + wn * 64 + ni * 16 + q;
          Cf[(size_t)m * N + n] = acc[mi][ni][r];
        }
      }
  } else {
    unsigned short* dst = (n0 < 1024) ? Cq : (n0 < 2048 ? Ck : Cv);
    const int obase = n0 & 1023;
#pragma unroll
    for (int mi = 0; mi < 4; ++mi)
#pragma unroll
      for (int r = 0; r < 4; ++r) {
        int m = m0 + wm * 64 + mi * 16 + g * 4 + r;
        int bb = m >> 11, s = m & 2047;
#pragma unroll
        for (int ni = 0; ni < 4; ++ni) {
          int o = obase + wn * 64 + ni * 16 + q;
          int hh = o >> 6, d = o & 63;
          dst[(((size_t)bb * 16 + hh) * 2048 + s) * 64 + d] = f2b(acc[mi][ni][r]);
        }
      }
  }
}

// ---------------- Flash attention (swapped-QK^T, 32x32 MFMA, in-register softmax) ---------
// Grid (64 heads, 16 q-blocks of 128). 4 warps x 32 q-rows. KVBLK=64.
// Swapped QK^T: S = mfma(K, Q) -> lane owns full P-row for q = lane&31.
// P -> PV A-frag via v_cvt_pk_bf16_f32 + v_permlane32_swap_b32 (no LDS round trip).
#define BUILD_PA(dst, SS, B) {                                        \
    unsigned X  = cvtpk_bf16(SS[B + 0], SS[B + 1]);                   \
    unsigned X2 = cvtpk_bf16(SS[B + 2], SS[B + 3]);                   \
    unsigned Y  = cvtpk_bf16(SS[B + 4], SS[B + 5]);                   \
    unsigned Y2 = cvtpk_bf16(SS[B + 6], SS[B + 7]);                   \
    asm volatile("v_permlane32_swap_b32 %0, %1" : "+v"(X), "+v"(Y));  \
    asm volatile("v_permlane32_swap_b32 %0, %1" : "+v"(X2), "+v"(Y2));\
    u32x4 pw_; pw_[0] = X; pw_[1] = X2; pw_[2] = Y; pw_[3] = Y2;      \
    dst = __builtin_bit_cast(s16x8, pw_); }

__global__ void attn_kernel(const unsigned short* __restrict__ Q, const unsigned short* __restrict__ K,
                            const unsigned short* __restrict__ V, unsigned short* __restrict__ O) {
  __shared__ __align__(16) unsigned short Ks[64 * 64];   // swizzled K tile
  __shared__ __align__(16) unsigned short Vt[64 * 72];   // V^T, padded stride 72
  const int t = threadIdx.x;
  const int lane = t & 63, w = t >> 6;
  const int h = lane >> 5, ql = lane & 31;
  const int bh = blockIdx.x;
  const int qt = 15 - (int)blockIdx.y;      // big q-blocks first
  const size_t hoff = (size_t)bh * 2048 * 64;
  const int q_global = qt * 128 + w * 32 + ql;
  const int qmax_w = qt * 128 + w * 32 + 31;

  // Q as B-fragments (col = q = lane&31, k = 8h + 16s + e); log2e*0.125 pre-folded by RoPE
  s16x8 qf[4];
  {
    const unsigned short* qp = Q + hoff + (size_t)q_global * 64 + h * 8;
#pragma unroll
    for (int s = 0; s < 4; ++s) qf[s] = *(const s16x8*)(qp + 16 * s);
  }
  f32x16 accO[2] = {};
  float mrun = -3e38f, lrun = 0.f;

  const int srow = t >> 3, scol = (t & 7) << 4;
  const int ntk = 2 * qt + 2;
  for (int tk = 0; tk < ntk; ++tk) {
    __syncthreads();
    // stage K (pre-swizzled source -> linear LDS, 16B global_load_lds)
    const char* kbp = (const char*)(K + hoff) + (size_t)tk * 8192;
#pragma unroll
    for (int it = 0; it < 2; ++it) {
      int row = it * 32 + srow;
      int cg = scol ^ ((row & 7) << 4);
      __builtin_amdgcn_global_load_lds(GLBP(kbp + row * 128 + cg),
                                       LDSP((char*)Ks + it * 4096 + w * 1024), 16, 0, 0);
    }
    // stage V transposed: Vt[d][kv], stride 72 (b16 writes, conflict-free)
    {
      const unsigned short* vbp = V + hoff + (size_t)tk * 4096;
#pragma unroll
      for (int p = 0; p < 2; ++p) {
        int d0 = w * 8 + p * 32;
        s16x8 vv = *(const s16x8*)(vbp + lane * 64 + d0);
#pragma unroll
        for (int j = 0; j < 8; ++j) Vt[(d0 + j) * 72 + lane] = (unsigned short)vv[j];
      }
    }
    asm volatile("s_waitcnt vmcnt(0)" ::: "memory");
    __syncthreads();
    if (tk * 64 > qmax_w) continue;   // warp fully above diagonal: staging+barrier only

    // ---- S^T = K * Q^T : lane holds P[kv(16 regs x 2 subtiles)][q = lane&31] ----
    f32x16 S0 = {}, S1 = {};
#pragma unroll
    for (int s = 0; s < 4; ++s) {
      const int cb = 16 * h + 32 * s;
      const int sw = (ql & 7) << 4;
      s16x8 kf0 = *(const s16x8*)((const char*)Ks + ql * 128 + (cb ^ sw));
      S0 = __builtin_amdgcn_mfma_f32_32x32x16_bf16(kf0, qf[s], S0, 0, 0, 0);
      s16x8 kf1 = *(const s16x8*)((const char*)Ks + (32 + ql) * 128 + (cb ^ sw));
      S1 = __builtin_amdgcn_mfma_f32_32x32x16_bf16(kf1, qf[s], S1, 0, 0, 0);
    }
    // ---- causal mask (diagonal region only): kv_global > q_global -> -inf ----
    if (tk * 64 + 63 > qt * 128 + w * 32) {
      const int kvb = tk * 64 + 4 * h;
#pragma unroll
      for (int r = 0; r < 16; ++r) {
        const int kvl = (r & 3) + 8 * (r >> 2);
        if (kvb + kvl > q_global) S0[r] = -3e38f;
        if (kvb + 32 + kvl > q_global) S1[r] = -3e38f;
      }
    }
    // ---- in-register online softmax (base-2) ----
    float pm = -3e38f;
#pragma unroll
    for (int r = 0; r < 16; ++r) pm = fmaxf(pm, fmaxf(S0[r], S1[r]));
    pm = fmaxf(pm, __shfl_xor(pm, 32));
    const float mnew = fmaxf(mrun, pm);
    const float alpha = exp2f(mrun - mnew);
    float ladd = 0.f;
#pragma unroll
    for (int r = 0; r < 16; ++r) {
      float p0 = exp2f(S0[r] - mnew);
      float p1 = exp2f(S1[r] - mnew);
      S0[r] = p0; S1[r] = p1;
      ladd += p0 + p1;
    }
    ladd += __shfl_xor(ladd, 32);
    lrun = lrun * alpha + ladd;
    mrun = mnew;
    if (__any(alpha < 1.0f)) {   // rescale O only when some row's max moved
#pragma unroll
      for (int r = 0; r < 16; ++r) {
        float ar = __shfl(alpha, 4 * h + (r & 3) + 8 * (r >> 2));
        accO[0][r] *= ar;
        accO[1][r] *= ar;
      }
    }
    // ---- P -> bf16 A-fragments in-register ----
    s16x8 pa[4];
    BUILD_PA(pa[0], S0, 0);
    BUILD_PA(pa[1], S0, 8);
    BUILD_PA(pa[2], S1, 0);
    BUILD_PA(pa[3], S1, 8);
    // ---- O += P * V ----
#pragma unroll
    for (int s = 0; s < 4; ++s) {
#pragma unroll
      for (int dt = 0; dt < 2; ++dt) {
        s16x8 vf = *(const s16x8*)(Vt + (dt * 32 + ql) * 72 + 8 * h + 16 * s);
        accO[dt] = __builtin_amdgcn_mfma_f32_32x32x16_bf16(pa[s], vf, accO[dt], 0, 0, 0);
      }
    }
  }
  // ---- epilogue: O /= l, write [b][s][h*64+d] bf16 ----
  const float linv = 1.0f / lrun;
  const int bb = bh >> 4, hh = bh & 15;
#pragma unroll
  for (int r = 0; r < 16; ++r) {
    const int qrow = 4 * h + (r & 3) + 8 * (r >> 2);
    const float lr = __shfl(linv, qrow);
    const int sg = qt * 128 + w * 32 + qrow;
    const size_t base = ((size_t)(bb * 2048 + sg)) * 1024 + hh * 64 + ql;
    O[base] = f2b(accO[0][r] * lr);
    O[base + 32] = f2b(accO[1][r] * lr);
  }
}

// ---------------- launch ----------------
extern "C" void kernel_launch(void* const* d_in, const int* in_sizes, int n_in,
                              void* d_out, int out_size, void* d_ws, size_t ws_size,
                              hipStream_t stream) {
  const float* x  = (const float*)d_in[0];
  const float* Wq = (const float*)d_in[1];
  const float* Wk = (const float*)d_in[2];
  const float* Wv = (const float*)d_in[3];
  const float* Wo = (const float*)d_in[4];
  char* ws = (char*)d_ws;
  unsigned short* xb   = (unsigned short*)(ws);               // 16 MB  [8192][1024]
  unsigned short* wqkv = (unsigned short*)(ws + 16777216);    // 6 MB   [3072][1024]
  unsigned short* wo   = (unsigned short*)(ws + 23068672);    // 2 MB   [1024][1024]
  unsigned short* qb   = (unsigned short*)(ws + 25165824);    // 16 MB  [64][2048][64]
  unsigned short* kb   = (unsigned short*)(ws + 41943040);    // 16 MB
  unsigned short* vb   = (unsigned short*)(ws + 58720256);    // 16 MB
  unsigned short* ab   = (unsigned short*)(ws + 75497472);    // 16 MB  [8192][1024]
  float* cosT = (float*)(ws + 92274688);                      // 256 KB
  float* sinT = (float*)(ws + 92536832);                      // 256 KB

  cvt_f2b_kernel<<<4096, 256, 0, stream>>>(x, xb, 1048576);
  cvt_f2b_kernel<<<512, 256, 0, stream>>>(Wq, wqkv, 131072);
  cvt_f2b_kernel<<<512, 256, 0, stream>>>(Wk, wqkv + 1048576, 131072);
  cvt_f2b_kernel<<<512, 256, 0, stream>>>(Wv, wqkv + 2097152, 131072);
  cvt_f2b_kernel<<<512, 256, 0, stream>>>(Wo, wo, 131072);
  rope_table_kernel<<<256, 256, 0, stream>>>(cosT, sinT);
  gemm_bt_kernel<1><<<dim3(64, 24), 256, 0, stream>>>(xb, wqkv, nullptr, qb, kb, vb, 8192, 3072, 1024);
  // Q scale folds 1/sqrt(dk) AND log2(e): attention softmax runs in base-2
  rope_apply_kernel<<<4096, 256, 0, stream>>>(qb, cosT, sinT, 0.125f * 1.44269504f);
  rope_apply_kernel<<<4096, 256, 0, stream>>>(kb, cosT, sinT, 1.0f);
  attn_kernel<<<dim3(64, 16), 256, 0, stream>>>(qb, kb, vb, ab);
  gemm_bt_kernel<0><<<dim3(64, 8), 256, 0, stream>>>(ab, wo, (float*)d_out, nullptr, nullptr, nullptr, 8192, 1024, 1024);
}

// Round 3
// 272.675 us; speedup vs baseline: 1.1165x; 1.0193x over previous
//
#include <hip/hip_runtime.h>
#include <hip/hip_bf16.h>
#include <math.h>

typedef __attribute__((ext_vector_type(4))) float f32x4;
typedef __attribute__((ext_vector_type(16))) float f32x16;
typedef __attribute__((ext_vector_type(8))) short s16x8;
typedef __attribute__((ext_vector_type(4))) unsigned u32x4;

#define LDSP(p) ((__attribute__((address_space(3))) void*)(p))
#define GLBP(p) ((const __attribute__((address_space(1))) void*)(p))

__device__ __forceinline__ unsigned short f2b(float f) {
  unsigned u = __builtin_bit_cast(unsigned, f);
  u += 0x7FFFu + ((u >> 16) & 1u);
  return (unsigned short)(u >> 16);
}
__device__ __forceinline__ float b2f(unsigned short h) {
  unsigned u = ((unsigned)h) << 16;
  return __builtin_bit_cast(float, u);
}
__device__ __forceinline__ unsigned cvtpk_bf16(float lo, float hi) {
  unsigned r;
  asm("v_cvt_pk_bf16_f32 %0, %1, %2" : "=v"(r) : "v"(lo), "v"(hi));
  return r;
}

// ---------------- fp32 -> bf16 convert (vectorized, 8 elems/thread) ----------------
__global__ void cvt_f2b_kernel(const float* __restrict__ src, unsigned short* __restrict__ dst, int n8) {
  int i = blockIdx.x * blockDim.x + threadIdx.x;
  if (i >= n8) return;
  const float4* s = (const float4*)src;
  float4 a = s[2 * i], b = s[2 * i + 1];
  s16x8 o;
  o[0] = (short)f2b(a.x); o[1] = (short)f2b(a.y); o[2] = (short)f2b(a.z); o[3] = (short)f2b(a.w);
  o[4] = (short)f2b(b.x); o[5] = (short)f2b(b.y); o[6] = (short)f2b(b.z); o[7] = (short)f2b(b.w);
  ((s16x8*)dst)[i] = o;
}

// ---------------- RoPE cos/sin table: [2048][32] ----------------
__global__ void rope_table_kernel(float* __restrict__ cosT, float* __restrict__ sinT) {
  int idx = blockIdx.x * 256 + threadIdx.x;  // 65536
  int s = idx >> 5, j = idx & 31;
  float freq = (float)(1.0 / pow(10000.0, (double)(2 * j) / 64.0));
  float fm = (float)s * freq;
  cosT[idx] = cosf(fm);
  sinT[idx] = sinf(fm);
}

// ---------------- RoPE in-place on [b*h][s][64] bf16, fused scale ----------------
__global__ void rope_apply_kernel(unsigned short* __restrict__ qk, const float* __restrict__ cosT,
                                  const float* __restrict__ sinT, float scale) {
  int i = blockIdx.x * 256 + threadIdx.x;  // 1048576 groups of 8 elems
  int e = i * 8;
  int s = (e >> 6) & 2047;
  int jb = (e & 63) >> 1;
  s16x8 v = ((const s16x8*)qk)[i];
  float4 c = *(const float4*)(cosT + s * 32 + jb);
  float4 sn = *(const float4*)(sinT + s * 32 + jb);
  float cc[4] = {c.x, c.y, c.z, c.w}, ss[4] = {sn.x, sn.y, sn.z, sn.w};
  s16x8 o;
#pragma unroll
  for (int p = 0; p < 4; ++p) {
    float e_ = b2f((unsigned short)v[2 * p]);
    float o_ = b2f((unsigned short)v[2 * p + 1]);
    o[2 * p]     = (short)f2b((e_ * cc[p] - o_ * ss[p]) * scale);
    o[2 * p + 1] = (short)f2b((e_ * ss[p] + o_ * cc[p]) * scale);
  }
  ((s16x8*)qk)[i] = o;
}

// ---------------- GEMM: C[m][n] = sum_k A[m][k] * B[n][k]  (B^T layout) ----------------
template <int EPI>
__global__ void gemm_bt_kernel(const unsigned short* __restrict__ A, const unsigned short* __restrict__ B,
                               float* __restrict__ Cf, unsigned short* __restrict__ Cq,
                               unsigned short* __restrict__ Ck, unsigned short* __restrict__ Cv,
                               int M, int N, int K) {
  __shared__ __align__(16) unsigned short As[128 * 64];
  __shared__ __align__(16) unsigned short Bs[128 * 64];
  const int t = threadIdx.x;
  const int lane = t & 63, wave = t >> 6;
  const int wm = wave >> 1, wn = wave & 1;
  const int g = lane >> 4, q = lane & 15;
  const int m0 = blockIdx.x * 128, n0 = blockIdx.y * 128;
  const int srow = t >> 3;
  const int scol = (t & 7) << 4;
  f32x4 acc[4][4] = {};
  const int nkt = K >> 6;
  for (int kt = 0; kt < nkt; ++kt) {
    __syncthreads();
#pragma unroll
    for (int it = 0; it < 4; ++it) {
      int row = it * 32 + srow;
      int cg = scol ^ ((row & 7) << 4);
      const char* ga = (const char*)A + ((size_t)(m0 + row) * K + (kt << 6)) * 2 + cg;
      __builtin_amdgcn_global_load_lds(GLBP(ga), LDSP((char*)As + it * 4096 + wave * 1024), 16, 0, 0);
      const char* gb = (const char*)B + ((size_t)(n0 + row) * K + (kt << 6)) * 2 + cg;
      __builtin_amdgcn_global_load_lds(GLBP(gb), LDSP((char*)Bs + it * 4096 + wave * 1024), 16, 0, 0);
    }
    asm volatile("s_waitcnt vmcnt(0)" ::: "memory");
    __syncthreads();
#pragma unroll
    for (int kk = 0; kk < 2; ++kk) {
      const int colB = ((kk << 6) + (g << 4)) ^ ((q & 7) << 4);
      s16x8 af[4], bf[4];
#pragma unroll
      for (int x = 0; x < 4; ++x) {
        af[x] = *(const s16x8*)(As + (wm * 64 + x * 16 + q) * 64 + (colB >> 1));
        bf[x] = *(const s16x8*)(Bs + (wn * 64 + x * 16 + q) * 64 + (colB >> 1));
      }
#pragma unroll
      for (int mi = 0; mi < 4; ++mi)
#pragma unroll
        for (int ni = 0; ni < 4; ++ni)
          acc[mi][ni] = __builtin_amdgcn_mfma_f32_16x16x32_bf16(af[mi], bf[ni], acc[mi][ni], 0, 0, 0);
    }
  }
  if (EPI == 0) {
#pragma unroll
    for (int mi = 0; mi < 4; ++mi)
#pragma unroll
      for (int r = 0; r < 4; ++r) {
        int m = m0 + wm * 64 + mi * 16 + g * 4 + r;
#pragma unroll
        for (int ni = 0; ni < 4; ++ni) {
          int n = n0 + wn * 64 + ni * 16 + q;
          Cf[(size_t)m * N + n] = acc[mi][ni][r];
        }
      }
  } else {
    unsigned short* dst = (n0 < 1024) ? Cq : (n0 < 2048 ? Ck : Cv);
    const int obase = n0 & 1023;
#pragma unroll
    for (int mi = 0; mi < 4; ++mi)
#pragma unroll
      for (int r = 0; r < 4; ++r) {
        int m = m0 + wm * 64 + mi * 16 + g * 4 + r;
        int bb = m >> 11, s = m & 2047;
#pragma unroll
        for (int ni = 0; ni < 4; ++ni) {
          int o = obase + wn * 64 + ni * 16 + q;
          int hh = o >> 6, d = o & 63;
          dst[(((size_t)bb * 16 + hh) * 2048 + s) * 64 + d] = f2b(acc[mi][ni][r]);
        }
      }
  }
}

// ---------------- Flash attention (swapped-QK^T, 32x32 MFMA, in-register softmax) ---------
// Grid (64 heads, 16 q-blocks of 128). 4 warps x 32 q-rows. KVBLK=64.
// Round-3: 2-phase double-buffered K/V staging (prefetch t+1 under compute of t),
// defer-max rescale (THR=8 in base-2), s_setprio around MFMA clusters.
#define BUILD_PA(dst, SS, B) {                                        \
    unsigned X  = cvtpk_bf16(SS[B + 0], SS[B + 1]);                   \
    unsigned X2 = cvtpk_bf16(SS[B + 2], SS[B + 3]);                   \
    unsigned Y  = cvtpk_bf16(SS[B + 4], SS[B + 5]);                   \
    unsigned Y2 = cvtpk_bf16(SS[B + 6], SS[B + 7]);                   \
    asm volatile("v_permlane32_swap_b32 %0, %1" : "+v"(X), "+v"(Y));  \
    asm volatile("v_permlane32_swap_b32 %0, %1" : "+v"(X2), "+v"(Y2));\
    u32x4 pw_; pw_[0] = X; pw_[1] = X2; pw_[2] = Y; pw_[3] = Y2;      \
    dst = __builtin_bit_cast(s16x8, pw_); }

__global__ void attn_kernel(const unsigned short* __restrict__ Q, const unsigned short* __restrict__ K,
                            const unsigned short* __restrict__ V, unsigned short* __restrict__ O) {
  __shared__ __align__(16) unsigned short Ks[2][64 * 64];   // swizzled K tiles (double-buffered)
  __shared__ __align__(16) unsigned short Vt[2][64 * 72];   // V^T, padded stride 72
  const int t = threadIdx.x;
  const int lane = t & 63, w = t >> 6;
  const int h = lane >> 5, ql = lane & 31;
  const int bh = blockIdx.x;
  const int qt = 15 - (int)blockIdx.y;      // big q-blocks first
  const size_t hoff = (size_t)bh * 2048 * 64;
  const int q_global = qt * 128 + w * 32 + ql;
  const int qmax_w = qt * 128 + w * 32 + 31;

  // Q as B-fragments (col = q = lane&31, k = 8h + 16s + e); log2e*0.125 pre-folded by RoPE
  s16x8 qf[4];
  {
    const unsigned short* qp = Q + hoff + (size_t)q_global * 64 + h * 8;
#pragma unroll
    for (int s = 0; s < 4; ++s) qf[s] = *(const s16x8*)(qp + 16 * s);
  }
  f32x16 accO[2] = {};
  float mrun = -3e38f, lrun = 0.f;

  const int srow = t >> 3, scol = (t & 7) << 4;   // K staging: 8 rows/wave, 16B chunks
  const int kv0 = 2 * (lane & 31);                // V staging: 2 kv rows per lane
  const int dbase = w * 16 + (lane >> 5) * 8;     //            16 d per wave
  const int ntk = 2 * qt + 2;
  s16x8 va = {}, vb2 = {};

  for (int it = 0; it <= ntk; ++it) {
    const int buf = it & 1;
    // ---- issue stage for tile `it` (K -> LDS via DMA, V -> regs) ----
    if (it < ntk) {
      const char* kbp = (const char*)(K + hoff) + (size_t)it * 8192;
#pragma unroll
      for (int p = 0; p < 2; ++p) {
        int row = p * 32 + srow;
        int cg = scol ^ ((row & 7) << 4);
        __builtin_amdgcn_global_load_lds(GLBP(kbp + row * 128 + cg),
                                         LDSP((char*)Ks[buf] + p * 4096 + w * 1024), 16, 0, 0);
      }
      const unsigned short* vbp = V + hoff + (size_t)it * 4096;
      va  = *(const s16x8*)(vbp + kv0 * 64 + dbase);
      vb2 = *(const s16x8*)(vbp + (kv0 + 1) * 64 + dbase);
    }
    // ---- compute tile it-1 (loads for `it` in flight underneath) ----
    const int tkc = it - 1;
    if (tkc >= 0 && tkc * 64 <= qmax_w) {
      const int cb2 = tkc & 1;
      // S^T = K * Q^T : lane holds P[kv regs][q = lane&31]
      f32x16 S0 = {}, S1 = {};
      __builtin_amdgcn_s_setprio(1);
#pragma unroll
      for (int s = 0; s < 4; ++s) {
        const int cb = 16 * h + 32 * s;
        const int sw = (ql & 7) << 4;
        s16x8 kf0 = *(const s16x8*)((const char*)Ks[cb2] + ql * 128 + (cb ^ sw));
        S0 = __builtin_amdgcn_mfma_f32_32x32x16_bf16(kf0, qf[s], S0, 0, 0, 0);
        s16x8 kf1 = *(const s16x8*)((const char*)Ks[cb2] + (32 + ql) * 128 + (cb ^ sw));
        S1 = __builtin_amdgcn_mfma_f32_32x32x16_bf16(kf1, qf[s], S1, 0, 0, 0);
      }
      __builtin_amdgcn_s_setprio(0);
      // causal mask (diagonal region only)
      if (tkc * 64 + 63 > qt * 128 + w * 32) {
        const int kvb = tkc * 64 + 4 * h;
#pragma unroll
        for (int r = 0; r < 16; ++r) {
          const int kvl = (r & 3) + 8 * (r >> 2);
          if (kvb + kvl > q_global) S0[r] = -3e38f;
          if (kvb + 32 + kvl > q_global) S1[r] = -3e38f;
        }
      }
      // online softmax (base-2) with defer-max: rescale only when max moved > 8
      float pm = -3e38f;
#pragma unroll
      for (int r = 0; r < 16; ++r) pm = fmaxf(pm, fmaxf(S0[r], S1[r]));
      pm = fmaxf(pm, __shfl_xor(pm, 32));
      if (!__all(pm - mrun <= 8.0f)) {
        const float mnew = fmaxf(mrun, pm);
        const float alpha = exp2f(mrun - mnew);
        lrun *= alpha;
#pragma unroll
        for (int r = 0; r < 16; ++r) {
          float ar = __shfl(alpha, 4 * h + (r & 3) + 8 * (r >> 2));
          accO[0][r] *= ar;
          accO[1][r] *= ar;
        }
        mrun = mnew;
      }
      float ladd = 0.f;
#pragma unroll
      for (int r = 0; r < 16; ++r) {
        float p0 = exp2f(S0[r] - mrun);
        float p1 = exp2f(S1[r] - mrun);
        S0[r] = p0; S1[r] = p1;
        ladd += p0 + p1;
      }
      ladd += __shfl_xor(ladd, 32);
      lrun += ladd;
      // P -> bf16 A-fragments in-register
      s16x8 pa[4];
      BUILD_PA(pa[0], S0, 0);
      BUILD_PA(pa[1], S0, 8);
      BUILD_PA(pa[2], S1, 0);
      BUILD_PA(pa[3], S1, 8);
      // O += P * V
      __builtin_amdgcn_s_setprio(1);
#pragma unroll
      for (int s = 0; s < 4; ++s) {
#pragma unroll
        for (int dt = 0; dt < 2; ++dt) {
          s16x8 vf = *(const s16x8*)(Vt[cb2] + (dt * 32 + ql) * 72 + 8 * h + 16 * s);
          accO[dt] = __builtin_amdgcn_mfma_f32_32x32x16_bf16(pa[s], vf, accO[dt], 0, 0, 0);
        }
      }
      __builtin_amdgcn_s_setprio(0);
    }
    // ---- drain tile-`it` loads; late V write (T14 split); publish ----
    asm volatile("s_waitcnt vmcnt(0)" ::: "memory");
    if (it < ntk) {
#pragma unroll
      for (int j = 0; j < 8; ++j) {
        unsigned pk = (unsigned)(unsigned short)va[j] | ((unsigned)(unsigned short)vb2[j] << 16);
        *(unsigned*)((char*)Vt[buf] + (size_t)((dbase + j) * 72 + kv0) * 2) = pk;
      }
    }
    __syncthreads();
  }
  // ---- epilogue: O /= l, write [b][s][h*64+d] bf16 ----
  const float linv = 1.0f / lrun;
  const int bb = bh >> 4, hh = bh & 15;
#pragma unroll
  for (int r = 0; r < 16; ++r) {
    const int qrow = 4 * h + (r & 3) + 8 * (r >> 2);
    const float lr = __shfl(linv, qrow);
    const int sg = qt * 128 + w * 32 + qrow;
    const size_t base = ((size_t)(bb * 2048 + sg)) * 1024 + hh * 64 + ql;
    O[base] = f2b(accO[0][r] * lr);
    O[base + 32] = f2b(accO[1][r] * lr);
  }
}

// ---------------- launch ----------------
extern "C" void kernel_launch(void* const* d_in, const int* in_sizes, int n_in,
                              void* d_out, int out_size, void* d_ws, size_t ws_size,
                              hipStream_t stream) {
  const float* x  = (const float*)d_in[0];
  const float* Wq = (const float*)d_in[1];
  const float* Wk = (const float*)d_in[2];
  const float* Wv = (const float*)d_in[3];
  const float* Wo = (const float*)d_in[4];
  char* ws = (char*)d_ws;
  unsigned short* xb   = (unsigned short*)(ws);               // 16 MB  [8192][1024]
  unsigned short* wqkv = (unsigned short*)(ws + 16777216);    // 6 MB   [3072][1024]
  unsigned short* wo   = (unsigned short*)(ws + 23068672);    // 2 MB   [1024][1024]
  unsigned short* qb   = (unsigned short*)(ws + 25165824);    // 16 MB  [64][2048][64]
  unsigned short* kb   = (unsigned short*)(ws + 41943040);    // 16 MB
  unsigned short* vb   = (unsigned short*)(ws + 58720256);    // 16 MB
  unsigned short* ab   = (unsigned short*)(ws + 75497472);    // 16 MB  [8192][1024]
  float* cosT = (float*)(ws + 92274688);                      // 256 KB
  float* sinT = (float*)(ws + 92536832);                      // 256 KB

  cvt_f2b_kernel<<<4096, 256, 0, stream>>>(x, xb, 1048576);
  cvt_f2b_kernel<<<512, 256, 0, stream>>>(Wq, wqkv, 131072);
  cvt_f2b_kernel<<<512, 256, 0, stream>>>(Wk, wqkv + 1048576, 131072);
  cvt_f2b_kernel<<<512, 256, 0, stream>>>(Wv, wqkv + 2097152, 131072);
  cvt_f2b_kernel<<<512, 256, 0, stream>>>(Wo, wo, 131072);
  rope_table_kernel<<<256, 256, 0, stream>>>(cosT, sinT);
  gemm_bt_kernel<1><<<dim3(64, 24), 256, 0, stream>>>(xb, wqkv, nullptr, qb, kb, vb, 8192, 3072, 1024);
  // Q scale folds 1/sqrt(dk) AND log2(e): attention softmax runs in base-2
  rope_apply_kernel<<<4096, 256, 0, stream>>>(qb, cosT, sinT, 0.125f * 1.44269504f);
  rope_apply_kernel<<<4096, 256, 0, stream>>>(kb, cosT, sinT, 1.0f);
  attn_kernel<<<dim3(64, 16), 256, 0, stream>>>(qb, kb, vb, ab);
  gemm_bt_kernel<0><<<dim3(64, 8), 256, 0, stream>>>(ab, wo, (float*)d_out, nullptr, nullptr, nullptr, 8192, 1024, 1024);
}